// Round 7
// baseline (775.865 us; speedup 1.0000x reference)
//
#include <hip/hip_runtime.h>
#include <hip/hip_bf16.h>
#include <math.h>

#define T_   32
#define C_   128
#define GD_  64
#define KQK_ 192
#define NH_  4
#define HD_  32
#define C4_  512
#define HW_  1024

typedef unsigned short u16;
typedef __attribute__((ext_vector_type(8))) short short8;
typedef __attribute__((ext_vector_type(4))) short short4v;
typedef __attribute__((ext_vector_type(4))) float f32x4;
typedef __attribute__((ext_vector_type(4))) unsigned short u16x4;

// ---- ws layout ----
#define ACF_A 0
#define ACF_C 512
#define WQH 2048
#define WQL 26624
#define WKH 51200
#define WKL 75776
#define WVH 100352
#define WVL 116736
#define W1H 133120
#define W1L 198656
#define W2H 264192
#define W2L 329728
#define GSH 395264
#define GSL 403456
#define XT  411648           // per-n interleaved: [n][hi 4096 u16 | lo 4096 u16]
#define WS_NEED_BYTES (823296ull + 4096ull*8192ull*2ull)   // 67,932,160

// ---- LDS pool byte offsets ----
// AX: [64][128] u16 per plane, stride 256 B, XOR-swizzled (T2). X2 overlays (same layout).
#define AXH 0          // 16384
#define AXL 16384      // ends 32768
// G (guidance, single copy): [32][64] u16 per plane, stride 128 B, swizzled. Dead after K GEMM.
#define GH  32768      // 4096
#define GL  36864      // ends 40960
// HM (half: 32 token rows): [32][128] u16 per plane, stride 256 B, swizzled. Overlays G region.
#define HMH 32768      // 8192
#define HML 40960      // ends 49152
#define KSUM  49152    // 256 f32: [tile*128 + head*32 + ch]
#define ZDEN  50176    // 256 f32: [tile*128 + head*32 + token]
#define STATS 51200    // 256 f32: mu1[64] rs1[64] mu2*rs2[64] rs2[64]  (global row)
#define LN2P  52224    // 512 f32: m[wv*64+row], s at +256
#define POOLB 54272    // 3 blocks/CU (163840/3 = 54613)

// XOR swizzle: 16B-block rotation keyed by row (T2). colb in bytes.
#define AXB(row, colb)  ((row)*256 + (((colb) ^ (((row)&7)<<4))))
#define GSW(row, colb)  ((row)*128 + (((colb) ^ (((row)&7)<<4))))

__device__ __forceinline__ float b2f(u16 u) {
    unsigned int x = ((unsigned int)u) << 16;
    float f; __builtin_memcpy(&f, &x, 4); return f;
}
__device__ __forceinline__ u16 f2b(float f) {
    __hip_bfloat16 h = __float2bfloat16(f);
    u16 u; __builtin_memcpy(&u, &h, 2); return u;
}
__device__ __forceinline__ void split2(float v, u16& h, u16& l) {
    h = f2b(v); l = f2b(v - b2f(h));
}
__device__ __forceinline__ void splitfrag(const f32x4 v, short4v& h, short4v& l) {
    u16 hh[4], ll[4];
    #pragma unroll
    for (int r = 0; r < 4; ++r) { hh[r] = f2b(v[r]); ll[r] = f2b(v[r] - b2f(hh[r])); }
    h = (short4v){(short)hh[0],(short)hh[1],(short)hh[2],(short)hh[3]};
    l = (short4v){(short)ll[0],(short)ll[1],(short)ll[2],(short)ll[3]};
}

__device__ __forceinline__ f32x4 mfma16(short4v a, short4v b, f32x4 c) {
#if __has_builtin(__builtin_amdgcn_mfma_f32_16x16x16bf16_1k)
    return __builtin_amdgcn_mfma_f32_16x16x16bf16_1k(a, b, c, 0, 0, 0);
#else
    asm("v_mfma_f32_16x16x16_bf16 %0, %1, %2, %0" : "+v"(c) : "v"(a), "v"(b));
    return c;
#endif
}

#define MFMA3(acc, ah, al, bh, bl)                                          \
    acc = __builtin_amdgcn_mfma_f32_16x16x32_bf16(ah, bh, acc, 0, 0, 0);    \
    acc = __builtin_amdgcn_mfma_f32_16x16x32_bf16(ah, bl, acc, 0, 0, 0);    \
    acc = __builtin_amdgcn_mfma_f32_16x16x32_bf16(al, bh, acc, 0, 0, 0);

#define MFMA3_16(acc, ah, al, bh, bl)                                       \
    acc = mfma16(ah, bh, acc);                                              \
    acc = mfma16(ah, bl, acc);                                              \
    acc = mfma16(al, bh, acc);

// ---- prep: split weights + guidance + a/cpl (unchanged) ----
__global__ void prep_weights(const float* __restrict__ Wq, const float* __restrict__ Wk,
                             const float* __restrict__ Wv, const float* __restrict__ W1,
                             const float* __restrict__ W2, const float* __restrict__ gui,
                             const float* __restrict__ g2, const float* __restrict__ be2,
                             const float* __restrict__ b1,
                             u16* __restrict__ wsp)
{
    int e = blockIdx.x * 256 + threadIdx.x;
    if (e >= 204800) {
        int n = e - 204800;
        if (n >= 512) return;
        float a = 0.f, c = 0.f;
        for (int k = 0; k < 128; ++k) {
            float w = W1[k*512 + n];
            a = fmaf(w, g2[k], a);
            c = fmaf(w, be2[k], c);
        }
        float* acf = (float*)wsp;
        acf[ACF_A + n] = a;
        acf[ACF_C + n] = c + b1[n];
        return;
    }
    if (e >= 196608) {
        int idx = e - 196608;
        float v = gui[idx];
        u16 hb = f2b(v);
        wsp[GSH + idx] = hb;
        wsp[GSL + idx] = f2b(v - b2f(hb));
        return;
    }
    const float* src; int e2, k, n, K; int oh, ol; int isW1 = 0;
    if (e < 24576)       { src = Wq; e2 = e;          k = e2 >> 7; n = e2 & 127; K = KQK_; oh = WQH; ol = WQL; }
    else if (e < 49152)  { src = Wk; e2 = e - 24576;  k = e2 >> 7; n = e2 & 127; K = KQK_; oh = WKH; ol = WKL; }
    else if (e < 65536)  { src = Wv; e2 = e - 49152;  k = e2 >> 7; n = e2 & 127; K = C_;   oh = WVH; ol = WVL; }
    else if (e < 131072) { src = W1; e2 = e - 65536;  k = e2 >> 9; n = e2 & 511; K = C_;   oh = W1H; ol = W1L; isW1 = 1; }
    else                 { src = W2; e2 = e - 131072; k = e2 >> 7; n = e2 & 127; K = C4_;  oh = W2H; ol = W2L; }
    float w = src[e2];
    if (isW1) w *= g2[k];
    u16 hb = f2b(w);
    wsp[oh + n * K + k] = hb;
    wsp[ol + n * K + k] = f2b(w - b2f(hb));
}

// ---- transpose x (unchanged) ----
__global__ __launch_bounds__(256) void transpose_x(const float* __restrict__ x, u16* __restrict__ wsp)
{
    __shared__ float tile[32][65];
    int bid = blockIdx.x;
    int hq = bid & 15, cq = (bid >> 4) & 3, t = (bid >> 6) & 31, b = bid >> 11;
    int c0 = cq * 32, hw0 = hq * 64;
    int tid = threadIdx.x;
    {
        int i = tid >> 3, j8 = (tid & 7) * 8;
        const float* src = x + ((size_t)((b*32 + t)*128 + c0 + i))*1024 + hw0 + j8;
        float4 v0 = *reinterpret_cast<const float4*>(src);
        float4 v1 = *reinterpret_cast<const float4*>(src + 4);
        tile[i][j8+0]=v0.x; tile[i][j8+1]=v0.y; tile[i][j8+2]=v0.z; tile[i][j8+3]=v0.w;
        tile[i][j8+4]=v1.x; tile[i][j8+5]=v1.y; tile[i][j8+6]=v1.z; tile[i][j8+7]=v1.w;
    }
    __syncthreads();
    {
        int jj = tid >> 2, c8 = (tid & 3) * 8;
        int n = b*1024 + hw0 + jj;
        u16 hh[8], ll[8];
        #pragma unroll
        for (int ii = 0; ii < 8; ++ii) {
            float v = tile[c8 + ii][jj];
            u16 hb = f2b(v);
            hh[ii] = hb; ll[ii] = f2b(v - b2f(hb));
        }
        u16* dh = wsp + XT + (size_t)n*8192 + t*128 + c0 + c8;
        u16* dl = dh + 4096;
        *reinterpret_cast<ushort4*>(dh)     = make_ushort4(hh[0],hh[1],hh[2],hh[3]);
        *reinterpret_cast<ushort4*>(dh + 4) = make_ushort4(hh[4],hh[5],hh[6],hh[7]);
        *reinterpret_cast<ushort4*>(dl)     = make_ushort4(ll[0],ll[1],ll[2],ll[3]);
        *reinterpret_cast<ushort4*>(dl + 4) = make_ushort4(ll[4],ll[5],ll[6],ll[7]);
    }
}

__global__ __launch_bounds__(256, 3) void fused_linattn_mfma(
    const float* __restrict__ x,
    const float* __restrict__ bq, const float* __restrict__ bk, const float* __restrict__ bv,
    const float* __restrict__ g1, const float* __restrict__ be1,
    const float* __restrict__ b2,
    const u16* __restrict__ wsp, int use_xt,
    float* __restrict__ out)
{
    extern __shared__ __align__(16) char pool[];
    float* ksum  = (float*)(pool + KSUM);
    float* zf    = (float*)(pool + ZDEN);
    float* stats = (float*)(pool + STATS);
    float* ln2p  = (float*)(pool + LN2P);
    const float* acf = (const float*)wsp;

    const int bi  = blockIdx.x;                    // 0..2047
    const int j_  = ((bi & 7) << 8) | (bi >> 3);   // XCD-chunked
    const int n0  = j_ * 2;                        // tiles n0, n0+1 (same b)
    const int b   = n0 >> 10;
    const int hw0 = n0 & 1023;
    const int tid = threadIdx.x;
    const int lane = tid & 63, wv = tid >> 6;      // wv = head 0..3
    const int l16  = lane & 15, quad = lane >> 4;

    // ---- Preload Q weight panel (hidden under phase A) ----
    short8 wqh[6][2], wql[6][2];
    #pragma unroll
    for (int ks = 0; ks < 6; ++ks)
        #pragma unroll
        for (int nt = 0; nt < 2; ++nt) {
            const int n = (wv*2 + nt)*16 + l16;
            wqh[ks][nt] = *(const short8*)(wsp + WQH + n*KQK_ + ks*32 + quad*8);
            wql[ks][nt] = *(const short8*)(wsp + WQL + n*KQK_ + ks*32 + quad*8);
        }

    // ---- Phase A: stage both tiles into AX (x only) + guidance into G ----
    if (use_xt) {
        #pragma unroll
        for (int tau = 0; tau < 2; ++tau) {
            const u16* xtb = wsp + XT + (size_t)(n0 + tau) * 8192;
            #pragma unroll
            for (int i = 0; i < 2; ++i) {
                int off = (tid + i*256) * 8;
                int t = off >> 7, c = off & 127;
                int grow = tau*32 + t;
                short8 vh = *reinterpret_cast<const short8*>(xtb + off);
                short8 vl = *reinterpret_cast<const short8*>(xtb + 4096 + off);
                *reinterpret_cast<short8*>(pool + AXH + AXB(grow, c*2)) = vh;
                *reinterpret_cast<short8*>(pool + AXL + AXB(grow, c*2)) = vl;
            }
        }
    } else {
        #pragma unroll
        for (int tau = 0; tau < 2; ++tau) {
            const float* xb = x + (size_t)b * (T_*C_*HW_) + hw0 + tau;
            #pragma unroll
            for (int i = 0; i < 16; ++i) {
                int idx = tid + i*256;
                float v = xb[(size_t)idx * HW_];
                int t = idx >> 7, c = idx & 127;
                int grow = tau*32 + t;
                u16 hb = f2b(v);
                *(u16*)(pool + AXH + AXB(grow, c*2)) = hb;
                *(u16*)(pool + AXL + AXB(grow, c*2)) = f2b(v - b2f(hb));
            }
        }
    }
    {   // guidance single copy: 32 rows x 64 u16 per plane
        const u16* gh = wsp + GSH + b*2048 + tid*8;
        const u16* gl = wsp + GSL + b*2048 + tid*8;
        int t = tid >> 3, jg = (tid & 7) * 8;
        short8 vh = *reinterpret_cast<const short8*>(gh);
        short8 vl = *reinterpret_cast<const short8*>(gl);
        *reinterpret_cast<short8*>(pool + GH + GSW(t, jg*2)) = vh;
        *reinterpret_cast<short8*>(pool + GL + GSW(t, jg*2)) = vl;
    }
    __syncthreads();

    // ---- Phase B: Q, K, V GEMMs over M=64 ----
    short4v qfh[4][2], qfl[4][2];   // [mt][dt]: Q' A-frag: row=token(l16), k=d(quad*4+i)
    short4v kfh[4][2], kfl[4][2];   // [mt][dt]: K' A-frag: row=d(l16), k=token(quad*4+i)
    short4v vfh[4][2], vfl[4][2];   // [mt][vt]: V  B-frag: col=v(l16), k=token(quad*4+i)

    // ---------------- Q (swapped: acc = [channel][token]) ----------------
    {
        f32x4 aq[4][2];
        #pragma unroll
        for (int mt = 0; mt < 4; ++mt)
            #pragma unroll
            for (int nt = 0; nt < 2; ++nt) aq[mt][nt] = (f32x4){0.f,0.f,0.f,0.f};
        #pragma unroll
        for (int ks = 0; ks < 6; ++ks) {
            short8 ah[4], al[4];
            if (ks < 4) {
                #pragma unroll
                for (int mt = 0; mt < 4; ++mt) {
                    ah[mt] = *(const short8*)(pool + AXH + AXB(mt*16 + l16, ks*64 + quad*16));
                    al[mt] = *(const short8*)(pool + AXL + AXB(mt*16 + l16, ks*64 + quad*16));
                }
            } else {
                #pragma unroll
                for (int mh2 = 0; mh2 < 2; ++mh2) {
                    int trow = mh2*16 + l16;
                    short8 gh2 = *(const short8*)(pool + GH + GSW(trow, (ks-4)*64 + quad*16));
                    short8 gl2 = *(const short8*)(pool + GL + GSW(trow, (ks-4)*64 + quad*16));
                    ah[mh2] = gh2; ah[mh2+2] = gh2;
                    al[mh2] = gl2; al[mh2+2] = gl2;
                }
            }
            #pragma unroll
            for (int nt = 0; nt < 2; ++nt)
                #pragma unroll
                for (int mt = 0; mt < 4; ++mt) { MFMA3(aq[mt][nt], wqh[ks][nt], wql[ks][nt], ah[mt], al[mt]); }
        }
        #pragma unroll
        for (int ct = 0; ct < 2; ++ct) {
            f32x4 bq4 = *(const f32x4*)(bq + wv*32 + ct*16 + quad*4);
            #pragma unroll
            for (int mt = 0; mt < 4; ++mt) {
                f32x4 qp;
                #pragma unroll
                for (int r = 0; r < 4; ++r) {
                    float q = aq[mt][ct][r] + bq4[r];
                    qp[r] = (q > 0.f) ? q + 1.f : __expf(q);
                }
                splitfrag(qp, qfh[mt][ct], qfl[mt][ct]);
            }
        }
    }

    // ---------------- K (normal: acc = [token][channel]) + ksum ----------------
    {
        f32x4 ak[4][2];
        #pragma unroll
        for (int mt = 0; mt < 4; ++mt)
            #pragma unroll
            for (int nt = 0; nt < 2; ++nt) ak[mt][nt] = (f32x4){0.f,0.f,0.f,0.f};
        #pragma unroll
        for (int ks = 0; ks < 6; ++ks) {
            short8 ah[4], al[4];
            if (ks < 4) {
                #pragma unroll
                for (int mt = 0; mt < 4; ++mt) {
                    ah[mt] = *(const short8*)(pool + AXH + AXB(mt*16 + l16, ks*64 + quad*16));
                    al[mt] = *(const short8*)(pool + AXL + AXB(mt*16 + l16, ks*64 + quad*16));
                }
            } else {
                #pragma unroll
                for (int mh2 = 0; mh2 < 2; ++mh2) {
                    int trow = mh2*16 + l16;
                    short8 gh2 = *(const short8*)(pool + GH + GSW(trow, (ks-4)*64 + quad*16));
                    short8 gl2 = *(const short8*)(pool + GL + GSW(trow, (ks-4)*64 + quad*16));
                    ah[mh2] = gh2; ah[mh2+2] = gh2;
                    al[mh2] = gl2; al[mh2+2] = gl2;
                }
            }
            #pragma unroll
            for (int nt = 0; nt < 2; ++nt) {
                const int n = (wv*2 + nt)*16 + l16;
                short8 bh = *(const short8*)(wsp + WKH + n*KQK_ + ks*32 + quad*8);
                short8 bl = *(const short8*)(wsp + WKL + n*KQK_ + ks*32 + quad*8);
                #pragma unroll
                for (int mt = 0; mt < 4; ++mt) { MFMA3(ak[mt][nt], ah[mt], al[mt], bh, bl); }
            }
        }
        float sk[2][2] = {{0.f,0.f},{0.f,0.f}};
        #pragma unroll
        for (int nt = 0; nt < 2; ++nt) {
            float bias = bk[wv*32 + nt*16 + l16];
            #pragma unroll
            for (int mt = 0; mt < 4; ++mt) {
                f32x4 kp;
                #pragma unroll
                for (int r = 0; r < 4; ++r) {
                    float k = ak[mt][nt][r] + bias;
                    float v = (k > 0.f) ? k + 1.f : __expf(k);
                    kp[r] = v;
                    sk[mt >> 1][nt] += v;
                }
                splitfrag(kp, kfh[mt][nt], kfl[mt][nt]);
            }
        }
        #pragma unroll
        for (int tau = 0; tau < 2; ++tau)
            #pragma unroll
            for (int nt = 0; nt < 2; ++nt) {
                float s = sk[tau][nt];
                s += __shfl_xor(s, 16); s += __shfl_xor(s, 32);
                if (quad == 0) ksum[tau*128 + wv*32 + nt*16 + l16] = s;
            }
    }

    // ---------------- V (normal) ----------------
    {
        f32x4 av[4][2];
        #pragma unroll
        for (int mt = 0; mt < 4; ++mt)
            #pragma unroll
            for (int nt = 0; nt < 2; ++nt) av[mt][nt] = (f32x4){0.f,0.f,0.f,0.f};
        #pragma unroll
        for (int ks = 0; ks < 4; ++ks) {
            short8 ah[4], al[4];
            #pragma unroll
            for (int mt = 0; mt < 4; ++mt) {
                ah[mt] = *(const short8*)(pool + AXH + AXB(mt*16 + l16, ks*64 + quad*16));
                al[mt] = *(const short8*)(pool + AXL + AXB(mt*16 + l16, ks*64 + quad*16));
            }
            #pragma unroll
            for (int nt = 0; nt < 2; ++nt) {
                const int n = (wv*2 + nt)*16 + l16;
                short8 bh = *(const short8*)(wsp + WVH + n*C_ + ks*32 + quad*8);
                short8 bl = *(const short8*)(wsp + WVL + n*C_ + ks*32 + quad*8);
                #pragma unroll
                for (int mt = 0; mt < 4; ++mt) { MFMA3(av[mt][nt], ah[mt], al[mt], bh, bl); }
            }
        }
        #pragma unroll
        for (int nt = 0; nt < 2; ++nt) {
            float bias = bv[wv*32 + nt*16 + l16];
            #pragma unroll
            for (int mt = 0; mt < 4; ++mt) {
                f32x4 vp;
                #pragma unroll
                for (int r = 0; r < 4; ++r) vp[r] = av[mt][nt][r] + bias;
                splitfrag(vp, vfh[mt][nt], vfl[mt][nt]);
            }
        }
    }

    // ---- zden (wave-local per tile) ----
    #pragma unroll
    for (int tau = 0; tau < 2; ++tau) {
        f32x4 ka0 = *(const f32x4*)(ksum + tau*128 + wv*32 + quad*4);
        f32x4 ka1 = *(const f32x4*)(ksum + tau*128 + wv*32 + 16 + quad*4);
        #pragma unroll
        for (int lt = 0; lt < 2; ++lt) {
            const int mt = tau*2 + lt;
            float p = 0.f;
            #pragma unroll
            for (int i = 0; i < 4; ++i) {
                p = fmaf(b2f((u16)(short)qfh[mt][0][i]) + b2f((u16)(short)qfl[mt][0][i]), ka0[i], p);
                p = fmaf(b2f((u16)(short)qfh[mt][1][i]) + b2f((u16)(short)qfl[mt][1][i]), ka1[i], p);
            }
            p += __shfl_xor(p, 16); p += __shfl_xor(p, 32);
            if (quad == 0) zf[tau*128 + wv*32 + lt*16 + l16] = 1.f / (p + 1e-6f);
        }
    }

    // ---- KV in registers per tile ----
    short4v kvfh[2][2][2], kvfl[2][2][2];   // [tau][dt][vt]
    #pragma unroll
    for (int tau = 0; tau < 2; ++tau)
        #pragma unroll
        for (int dt = 0; dt < 2; ++dt)
            #pragma unroll
            for (int vt = 0; vt < 2; ++vt) {
                f32x4 kv = (f32x4){0.f,0.f,0.f,0.f};
                #pragma unroll
                for (int lt = 0; lt < 2; ++lt) {
                    const int mt = tau*2 + lt;
                    MFMA3_16(kv, kfh[mt][dt], kfl[mt][dt], vfh[mt][vt], vfl[mt][vt]);
                }
                splitfrag(kv, kvfh[tau][dt][vt], kvfl[tau][dt][vt]);
            }

    // ---- ln1 stats (4 threads/row, 64 rows; x channels only) ----
    {
        int t = tid >> 2, jj = tid & 3;
        float m = 0.f, s = 0.f;
        #pragma unroll
        for (int p8 = 0; p8 < 4; ++p8) {
            int colb = jj*64 + p8*16;
            short8 h = *(const short8*)(pool + AXH + AXB(t, colb));
            short8 l = *(const short8*)(pool + AXL + AXB(t, colb));
            #pragma unroll
            for (int i = 0; i < 8; ++i) {
                float v = b2f((u16)h[i]) + b2f((u16)l[i]);
                m += v; s = fmaf(v, v, s);
            }
        }
        m += __shfl_xor(m, 1); s += __shfl_xor(s, 1);
        m += __shfl_xor(m, 2); s += __shfl_xor(s, 2);
        if (jj == 0) {
            float mu = m * (1.f/C_);
            stats[t]      = mu;
            stats[64 + t] = rsqrtf(s * (1.f/C_) - mu*mu + 1e-5f);
        }
    }
    __syncthreads();

    // ---- Phase O: o = Q' x KV + zden + ln1 residual ----
    f32x4 o1v[4][2];   // [mt][vt]: row = mt*16+quad*4+r, ch = wv*32+vt*16+l16
    #pragma unroll
    for (int mt = 0; mt < 4; ++mt) {
        const int tau = mt >> 1;
        f32x4 zd4 = *(const f32x4*)(zf + tau*128 + wv*32 + (mt & 1)*16 + quad*4);
        f32x4 mu4 = *(const f32x4*)(stats + mt*16 + quad*4);
        f32x4 rs4 = *(const f32x4*)(stats + 64 + mt*16 + quad*4);
        #pragma unroll
        for (int vt = 0; vt < 2; ++vt) {
            f32x4 oa = (f32x4){0.f,0.f,0.f,0.f};
            #pragma unroll
            for (int dt = 0; dt < 2; ++dt) {
                MFMA3_16(oa, qfh[mt][dt], qfl[mt][dt], kvfh[tau][dt][vt], kvfl[tau][dt][vt]);
            }
            int ch = wv*32 + vt*16 + l16;
            float g1c = g1[ch], be1c = be1[ch];
            #pragma unroll
            for (int r = 0; r < 4; ++r) {
                int row = mt*16 + quad*4 + r;
                float xv = b2f(*(const u16*)(pool + AXH + AXB(row, ch*2)))
                         + b2f(*(const u16*)(pool + AXL + AXB(row, ch*2)));
                o1v[mt][vt][r] = oa[r]*zd4[r] + (xv - mu4[r])*rs4[r]*g1c + be1c;
            }
        }
    }
    // ln2 partials: per wave over its 32 channels per row
    {
        #pragma unroll
        for (int mt = 0; mt < 4; ++mt)
            #pragma unroll
            for (int r = 0; r < 4; ++r) {
                float v0 = o1v[mt][0][r], v1 = o1v[mt][1][r];
                float m = v0 + v1;
                float s = v0*v0 + v1*v1;
                m += __shfl_xor(m, 1); s += __shfl_xor(s, 1);
                m += __shfl_xor(m, 2); s += __shfl_xor(s, 2);
                m += __shfl_xor(m, 4); s += __shfl_xor(s, 4);
                m += __shfl_xor(m, 8); s += __shfl_xor(s, 8);
                if (l16 == 0) {
                    int row = mt*16 + quad*4 + r;
                    ln2p[wv*64 + row]       = m;
                    ln2p[256 + wv*64 + row] = s;
                }
            }
    }
    __syncthreads();   // AX dead; LN2P visible

    // ---- X2 = raw o1 split planes (overlays AX, same swizzled layout) ----
    #pragma unroll
    for (int mt = 0; mt < 4; ++mt) {
        #pragma unroll
        for (int vt = 0; vt < 2; ++vt) {
            int ch = wv*32 + vt*16 + l16;
            #pragma unroll
            for (int r = 0; r < 4; ++r) {
                int row = mt*16 + quad*4 + r;
                u16 hb, lb; split2(o1v[mt][vt][r], hb, lb);
                *(u16*)(pool + AXH + AXB(row, ch*2)) = hb;
                *(u16*)(pool + AXL + AXB(row, ch*2)) = lb;
            }
        }
    }
    if (tid < 64) {    // ln2 finalize (global row)
        int t = tid;
        float m = 0.f, s = 0.f;
        #pragma unroll
        for (int w = 0; w < 4; ++w) { m += ln2p[w*64 + t]; s += ln2p[256 + w*64 + t]; }
        float mu = m * (1.f/C_);
        float rs = rsqrtf(s * (1.f/C_) - mu*mu + 1e-5f);
        stats[128 + t] = mu * rs;
        stats[192 + t] = rs;
    }
    __syncthreads();

    // ---- Phases F/G: MLP, 4 chunks x 2 row-halves; HM buffer is 32 rows ----
    f32x4 accO[4][2];   // [mt][nt]: row = mt*16+quad*4+r, out_ch = (wv*2+nt)*16+l16
    #pragma unroll
    for (int mt = 0; mt < 4; ++mt)
        #pragma unroll
        for (int nt = 0; nt < 2; ++nt) accO[mt][nt] = (f32x4){0.f,0.f,0.f,0.f};

    #pragma unroll 1
    for (int mh = 0; mh < 4; ++mh) {
        #pragma unroll 1
        for (int half = 0; half < 2; ++half) {
            {
                f32x4 accH[2][2];
                #pragma unroll
                for (int mtl = 0; mtl < 2; ++mtl)
                    #pragma unroll
                    for (int nt = 0; nt < 2; ++nt) accH[mtl][nt] = (f32x4){0.f,0.f,0.f,0.f};
                #pragma unroll
                for (int ks = 0; ks < 4; ++ks) {
                    short8 ah[2], al[2];
                    #pragma unroll
                    for (int mtl = 0; mtl < 2; ++mtl) {
                        int row = (half*2 + mtl)*16 + l16;
                        ah[mtl] = *(const short8*)(pool + AXH + AXB(row, ks*64 + quad*16));
                        al[mtl] = *(const short8*)(pool + AXL + AXB(row, ks*64 + quad*16));
                    }
                    #pragma unroll
                    for (int nt = 0; nt < 2; ++nt) {
                        const int gn = mh*128 + (wv*2 + nt)*16 + l16;
                        short8 bh = *(const short8*)(wsp + W1H + gn*C_ + ks*32 + quad*8);
                        short8 bl = *(const short8*)(wsp + W1L + gn*C_ + ks*32 + quad*8);
                        #pragma unroll
                        for (int mtl = 0; mtl < 2; ++mtl) { MFMA3(accH[mtl][nt], bh, bl, ah[mtl], al[mtl]); }
                    }
                }
                // F epilogue: folded-ln2 + gelu -> HM (32 rows)
                #pragma unroll
                for (int nt = 0; nt < 2; ++nt) {
                    int base = mh*128 + (wv*2 + nt)*16 + quad*4;
                    f32x4 a4 = *(const f32x4*)(acf + ACF_A + base);
                    f32x4 c4 = *(const f32x4*)(acf + ACF_C + base);
                    int ch0 = (wv*2 + nt)*16 + quad*4;
                    #pragma unroll
                    for (int mtl = 0; mtl < 2; ++mtl) {
                        int tk = mtl*16 + l16;               // HM row
                        int tkg = half*32 + tk;              // global row
                        float mrs = stats[128 + tkg], rsv = stats[192 + tkg];
                        u16 hh[4], ll[4];
                        #pragma unroll
                        for (int r = 0; r < 4; ++r) {
                            float v = accH[mtl][nt][r]*rsv - mrs*a4[r] + c4[r];
                            float ge = 0.5f * v * (1.f + erff(v * 0.70710678118654752f));
                            split2(ge, hh[r], ll[r]);
                        }
                        *(u16x4*)(pool + HMH + AXB(tk, ch0*2)) = (u16x4){hh[0],hh[1],hh[2],hh[3]};
                        *(u16x4*)(pool + HML + AXB(tk, ch0*2)) = (u16x4){ll[0],ll[1],ll[2],ll[3]};
                    }
                }
            }
            __syncthreads();
            {
                #pragma unroll
                for (int ks = 0; ks < 4; ++ks) {
                    short8 ah[2], al[2];
                    #pragma unroll
                    for (int mtl = 0; mtl < 2; ++mtl) {
                        int row = mtl*16 + l16;
                        ah[mtl] = *(const short8*)(pool + HMH + AXB(row, ks*64 + quad*16));
                        al[mtl] = *(const short8*)(pool + HML + AXB(row, ks*64 + quad*16));
                    }
                    #pragma unroll
                    for (int nt = 0; nt < 2; ++nt) {
                        const int n = (wv*2 + nt)*16 + l16;
                        short8 bh = *(const short8*)(wsp + W2H + n*C4_ + mh*128 + ks*32 + quad*8);
                        short8 bl = *(const short8*)(wsp + W2L + n*C4_ + mh*128 + ks*32 + quad*8);
                        #pragma unroll
                        for (int mtl = 0; mtl < 2; ++mtl) { MFMA3(accO[half*2 + mtl][nt], ah[mtl], al[mtl], bh, bl); }
                    }
                }
            }
            if (!(mh == 3 && half == 1)) __syncthreads();
        }
    }

    // ---- Epilogue: y = o1v + mlp + b2, strided store (two tiles) ----
    {
        float* obase = out + (size_t)b * (T_*C_*HW_) + hw0;
        #pragma unroll
        for (int mt = 0; mt < 4; ++mt) {
            const int tau = mt >> 1;
            float* ob = obase + tau;
            #pragma unroll
            for (int nt = 0; nt < 2; ++nt) {
                int ch = wv*32 + nt*16 + l16;
                float b2c = b2[ch];
                #pragma unroll
                for (int r = 0; r < 4; ++r) {
                    int t = (mt & 1)*16 + quad*4 + r;
                    float y = o1v[mt][nt][r] + accO[mt][nt][r] + b2c;
                    ob[(size_t)(t*C_ + ch) * HW_] = y;
                }
            }
        }
    }
}

extern "C" void kernel_launch(void* const* d_in, const int* in_sizes, int n_in,
                              void* d_out, int out_size, void* d_ws, size_t ws_size,
                              hipStream_t stream)
{
    const float* x   = (const float*)d_in[0];
    const float* gui = (const float*)d_in[1];
    const float* Wq  = (const float*)d_in[2];
    const float* bq  = (const float*)d_in[3];
    const float* Wk  = (const float*)d_in[4];
    const float* bk  = (const float*)d_in[5];
    const float* Wv  = (const float*)d_in[6];
    const float* bv  = (const float*)d_in[7];
    const float* g1  = (const float*)d_in[8];
    const float* be1 = (const float*)d_in[9];
    const float* g2  = (const float*)d_in[10];
    const float* be2 = (const float*)d_in[11];
    const float* W1  = (const float*)d_in[12];
    const float* b1  = (const float*)d_in[13];
    const float* W2  = (const float*)d_in[14];
    const float* b2  = (const float*)d_in[15];
    u16* wsp = (u16*)d_ws;

    int use_xt = (ws_size >= WS_NEED_BYTES) ? 1 : 0;

    prep_weights<<<dim3(802), dim3(256), 0, stream>>>(Wq, Wk, Wv, W1, W2, gui, g2, be2, b1, wsp);
    if (use_xt)
        transpose_x<<<dim3(8192), dim3(256), 0, stream>>>(x, wsp);

    (void)hipFuncSetAttribute((const void*)fused_linattn_mfma,
                              hipFuncAttributeMaxDynamicSharedMemorySize,
                              POOLB);
    fused_linattn_mfma<<<dim3(2048), dim3(256), POOLB, stream>>>(
        x, bq, bk, bv, g1, be1, b2, wsp, use_xt, (float*)d_out);
}

// Round 8
// 485.574 us; speedup vs baseline: 1.5978x; 1.5978x over previous
//
#include <hip/hip_runtime.h>
#include <hip/hip_bf16.h>
#include <math.h>

#define T_   32
#define C_   128
#define GD_  64
#define KQK_ 192
#define NH_  4
#define HD_  32
#define C4_  512
#define HW_  1024

typedef unsigned short u16;
typedef __attribute__((ext_vector_type(8))) short short8;
typedef __attribute__((ext_vector_type(4))) short short4v;
typedef __attribute__((ext_vector_type(4))) float f32x4;
typedef __attribute__((ext_vector_type(4))) unsigned short u16x4;

// ---- ws layout ----
#define ACF_A 0
#define ACF_C 512
#define WQH 2048
#define WQL 26624
#define WKH 51200
#define WKL 75776
#define WVH 100352
#define WVL 116736
#define W1H 133120
#define W1L 198656
#define W2H 264192
#define W2L 329728
#define GSH 395264
#define GSL 403456
#define XT  411648           // per-n interleaved: [n][hi 4096 u16 | lo 4096 u16]
#define WS_NEED_BYTES (823296ull + 4096ull*8192ull*2ull)   // 67,932,160

// ---- LDS pool byte offsets (M=64: two sequences per block) ----
#define AX_H  0        // [64][200] u16 (x|g hi), stride 400 B; rows 0-31 tile0, 32-63 tile1
#define AX_L  25600    // lo plane, ends 51200
// X2: 4 groups of 16 rows, overlaying AX after it dies. group g at g*8704:
//   h [16][136] stride 272 at +0, l at +4352. Ends 34816.
#define X2G(g) ((g)*8704)
#define HM_H  34816    // [64][136] u16 stride 272 (h), 17408 B
#define HM_L  52224    // lo plane, ends 69632
#define KSUM  69632    // 256 f32: [tile][128]
#define ZDEN  70656    // 256 f32: [tile][head*32+token]
#define STATS 71680    // 256 f32: mu1[64] rs1[64] mu2*rs2[64] rs2[64]
#define LN2P  72704    // 512 f32: m[4 waves][64 rows], s[4][64]
#define POOLB 74752    // 2 blocks/CU (163840/2 = 81920)

__device__ __forceinline__ float b2f(u16 u) {
    unsigned int x = ((unsigned int)u) << 16;
    float f; __builtin_memcpy(&f, &x, 4); return f;
}
__device__ __forceinline__ u16 f2b(float f) {
    __hip_bfloat16 h = __float2bfloat16(f);
    u16 u; __builtin_memcpy(&u, &h, 2); return u;
}
__device__ __forceinline__ void split2(float v, u16& h, u16& l) {
    h = f2b(v); l = f2b(v - b2f(h));
}
__device__ __forceinline__ void splitfrag(const f32x4 v, short4v& h, short4v& l) {
    u16 hh[4], ll[4];
    #pragma unroll
    for (int r = 0; r < 4; ++r) { hh[r] = f2b(v[r]); ll[r] = f2b(v[r] - b2f(hh[r])); }
    h = (short4v){(short)hh[0],(short)hh[1],(short)hh[2],(short)hh[3]};
    l = (short4v){(short)ll[0],(short)ll[1],(short)ll[2],(short)ll[3]};
}

__device__ __forceinline__ f32x4 mfma16(short4v a, short4v b, f32x4 c) {
#if __has_builtin(__builtin_amdgcn_mfma_f32_16x16x16bf16_1k)
    return __builtin_amdgcn_mfma_f32_16x16x16bf16_1k(a, b, c, 0, 0, 0);
#else
    asm("v_mfma_f32_16x16x16_bf16 %0, %1, %2, %0" : "+v"(c) : "v"(a), "v"(b));
    return c;
#endif
}

#define MFMA3(acc, ah, al, bh, bl)                                          \
    acc = __builtin_amdgcn_mfma_f32_16x16x32_bf16(ah, bh, acc, 0, 0, 0);    \
    acc = __builtin_amdgcn_mfma_f32_16x16x32_bf16(ah, bl, acc, 0, 0, 0);    \
    acc = __builtin_amdgcn_mfma_f32_16x16x32_bf16(al, bh, acc, 0, 0, 0);

#define MFMA3_16(acc, ah, al, bh, bl)                                       \
    acc = mfma16(ah, bh, acc);                                              \
    acc = mfma16(ah, bl, acc);                                              \
    acc = mfma16(al, bh, acc);

// ---- prep: split weights + guidance + a/cpl (unchanged) ----
__global__ void prep_weights(const float* __restrict__ Wq, const float* __restrict__ Wk,
                             const float* __restrict__ Wv, const float* __restrict__ W1,
                             const float* __restrict__ W2, const float* __restrict__ gui,
                             const float* __restrict__ g2, const float* __restrict__ be2,
                             const float* __restrict__ b1,
                             u16* __restrict__ wsp)
{
    int e = blockIdx.x * 256 + threadIdx.x;
    if (e >= 204800) {
        int n = e - 204800;
        if (n >= 512) return;
        float a = 0.f, c = 0.f;
        for (int k = 0; k < 128; ++k) {
            float w = W1[k*512 + n];
            a = fmaf(w, g2[k], a);
            c = fmaf(w, be2[k], c);
        }
        float* acf = (float*)wsp;
        acf[ACF_A + n] = a;
        acf[ACF_C + n] = c + b1[n];
        return;
    }
    if (e >= 196608) {
        int idx = e - 196608;
        float v = gui[idx];
        u16 hb = f2b(v);
        wsp[GSH + idx] = hb;
        wsp[GSL + idx] = f2b(v - b2f(hb));
        return;
    }
    const float* src; int e2, k, n, K; int oh, ol; int isW1 = 0;
    if (e < 24576)       { src = Wq; e2 = e;          k = e2 >> 7; n = e2 & 127; K = KQK_; oh = WQH; ol = WQL; }
    else if (e < 49152)  { src = Wk; e2 = e - 24576;  k = e2 >> 7; n = e2 & 127; K = KQK_; oh = WKH; ol = WKL; }
    else if (e < 65536)  { src = Wv; e2 = e - 49152;  k = e2 >> 7; n = e2 & 127; K = C_;   oh = WVH; ol = WVL; }
    else if (e < 131072) { src = W1; e2 = e - 65536;  k = e2 >> 9; n = e2 & 511; K = C_;   oh = W1H; ol = W1L; isW1 = 1; }
    else                 { src = W2; e2 = e - 131072; k = e2 >> 7; n = e2 & 127; K = C4_;  oh = W2H; ol = W2L; }
    float w = src[e2];
    if (isW1) w *= g2[k];
    u16 hb = f2b(w);
    wsp[oh + n * K + k] = hb;
    wsp[ol + n * K + k] = f2b(w - b2f(hb));
}

// ---- transpose x (unchanged) ----
__global__ __launch_bounds__(256) void transpose_x(const float* __restrict__ x, u16* __restrict__ wsp)
{
    __shared__ float tile[32][65];
    int bid = blockIdx.x;
    int hq = bid & 15, cq = (bid >> 4) & 3, t = (bid >> 6) & 31, b = bid >> 11;
    int c0 = cq * 32, hw0 = hq * 64;
    int tid = threadIdx.x;
    {
        int i = tid >> 3, j8 = (tid & 7) * 8;
        const float* src = x + ((size_t)((b*32 + t)*128 + c0 + i))*1024 + hw0 + j8;
        float4 v0 = *reinterpret_cast<const float4*>(src);
        float4 v1 = *reinterpret_cast<const float4*>(src + 4);
        tile[i][j8+0]=v0.x; tile[i][j8+1]=v0.y; tile[i][j8+2]=v0.z; tile[i][j8+3]=v0.w;
        tile[i][j8+4]=v1.x; tile[i][j8+5]=v1.y; tile[i][j8+6]=v1.z; tile[i][j8+7]=v1.w;
    }
    __syncthreads();
    {
        int jj = tid >> 2, c8 = (tid & 3) * 8;
        int n = b*1024 + hw0 + jj;
        u16 hh[8], ll[8];
        #pragma unroll
        for (int ii = 0; ii < 8; ++ii) {
            float v = tile[c8 + ii][jj];
            u16 hb = f2b(v);
            hh[ii] = hb; ll[ii] = f2b(v - b2f(hb));
        }
        u16* dh = wsp + XT + (size_t)n*8192 + t*128 + c0 + c8;
        u16* dl = dh + 4096;
        *reinterpret_cast<ushort4*>(dh)     = make_ushort4(hh[0],hh[1],hh[2],hh[3]);
        *reinterpret_cast<ushort4*>(dh + 4) = make_ushort4(hh[4],hh[5],hh[6],hh[7]);
        *reinterpret_cast<ushort4*>(dl)     = make_ushort4(ll[0],ll[1],ll[2],ll[3]);
        *reinterpret_cast<ushort4*>(dl + 4) = make_ushort4(ll[4],ll[5],ll[6],ll[7]);
    }
}

__global__ __launch_bounds__(256, 2) void fused_linattn_mfma(
    const float* __restrict__ x,
    const float* __restrict__ bq, const float* __restrict__ bk, const float* __restrict__ bv,
    const float* __restrict__ g1, const float* __restrict__ be1,
    const float* __restrict__ b2,
    const u16* __restrict__ wsp, int use_xt,
    float* __restrict__ out)
{
    extern __shared__ __align__(16) char pool[];
    float* ksum  = (float*)(pool + KSUM);
    float* zf    = (float*)(pool + ZDEN);
    float* stats = (float*)(pool + STATS);
    float* ln2p  = (float*)(pool + LN2P);
    const float* acf = (const float*)wsp;

    const int bi  = blockIdx.x;                    // 0..2047
    const int j_  = ((bi & 7) << 8) | (bi >> 3);   // XCD-chunked
    const int n0  = j_ * 2;                        // tiles n0, n0+1 (same b)
    const int b   = n0 >> 10;
    const int hw0 = n0 & 1023;
    const int tid = threadIdx.x;
    const int lane = tid & 63, wv = tid >> 6;
    const int l16  = lane & 15, quad = lane >> 4;

    // ---- Preload Q weight panel (hidden under phase A) ----
    short8 wqh[6][2], wql[6][2];
    #pragma unroll
    for (int ks = 0; ks < 6; ++ks)
        #pragma unroll
        for (int nt = 0; nt < 2; ++nt) {
            const int n = (wv*2 + nt)*16 + l16;
            wqh[ks][nt] = *(const short8*)(wsp + WQH + n*KQK_ + ks*32 + quad*8);
            wql[ks][nt] = *(const short8*)(wsp + WQL + n*KQK_ + ks*32 + quad*8);
        }

    // ---- Phase A: stage both tiles into AX ----
    if (use_xt) {
        #pragma unroll
        for (int tau = 0; tau < 2; ++tau) {
            const u16* xtb = wsp + XT + (size_t)(n0 + tau) * 8192;
            #pragma unroll
            for (int i = 0; i < 2; ++i) {
                int off = (tid + i*256) * 8;
                int t = off >> 7, c = off & 127;
                short8 vh = *reinterpret_cast<const short8*>(xtb + off);
                short8 vl = *reinterpret_cast<const short8*>(xtb + 4096 + off);
                *reinterpret_cast<short8*>(pool + AX_H + (tau*32 + t)*400 + c*2) = vh;
                *reinterpret_cast<short8*>(pool + AX_L + (tau*32 + t)*400 + c*2) = vl;
            }
        }
    } else {
        #pragma unroll
        for (int tau = 0; tau < 2; ++tau) {
            const float* xb = x + (size_t)b * (T_*C_*HW_) + hw0 + tau;
            #pragma unroll
            for (int i = 0; i < 16; ++i) {
                int idx = tid + i*256;
                float v = xb[(size_t)idx * HW_];
                int t = idx >> 7, c = idx & 127;
                u16 hb = f2b(v);
                *(u16*)(pool + AX_H + (tau*32 + t)*400 + c*2) = hb;
                *(u16*)(pool + AX_L + (tau*32 + t)*400 + c*2) = f2b(v - b2f(hb));
            }
        }
    }
    {   // guidance: same b for both tiles -> write rows t and t+32
        const u16* gh = wsp + GSH + b*2048 + tid*8;
        const u16* gl = wsp + GSL + b*2048 + tid*8;
        int off = tid * 8;
        int t = off >> 6, jg = off & 63;
        short8 vh = *reinterpret_cast<const short8*>(gh);
        short8 vl = *reinterpret_cast<const short8*>(gl);
        *reinterpret_cast<short8*>(pool + AX_H + t*400 + 256 + jg*2) = vh;
        *reinterpret_cast<short8*>(pool + AX_L + t*400 + 256 + jg*2) = vl;
        *reinterpret_cast<short8*>(pool + AX_H + (32 + t)*400 + 256 + jg*2) = vh;
        *reinterpret_cast<short8*>(pool + AX_L + (32 + t)*400 + 256 + jg*2) = vl;
    }
    __syncthreads();

    // ---- Phase B: Q, K, V GEMMs over M=64, panels preloaded one GEMM ahead ----
    short4v qfh[4][2], qfl[4][2];   // [mt][dt]: Q' A-frag: row=token(l16), k=d(quad*4+i)
    short4v kfh[4][2], kfl[4][2];   // [mt][dt]: K' A-frag: row=d(l16), k=token(quad*4+i)
    short4v vfh[4][2], vfl[4][2];   // [mt][vt]: V  B-frag: col=v(l16), k=token(quad*4+i)
    short8 wkh[6][2], wkl[6][2];
    short8 wvh[4][2], wvl[4][2];

    // ---------------- Q (swapped: acc = [channel][token]) ----------------
    {
        f32x4 aq[4][2];
        #pragma unroll
        for (int mt = 0; mt < 4; ++mt)
            #pragma unroll
            for (int nt = 0; nt < 2; ++nt) aq[mt][nt] = (f32x4){0.f,0.f,0.f,0.f};
        #pragma unroll
        for (int ks = 0; ks < 6; ++ks) {
            short8 ah[4], al[4];
            #pragma unroll
            for (int mt = 0; mt < 4; ++mt) {
                ah[mt] = *(const short8*)(pool + AX_H + (mt*16 + l16)*400 + ks*64 + quad*16);
                al[mt] = *(const short8*)(pool + AX_L + (mt*16 + l16)*400 + ks*64 + quad*16);
            }
            #pragma unroll
            for (int nt = 0; nt < 2; ++nt)
                #pragma unroll
                for (int mt = 0; mt < 4; ++mt) { MFMA3(aq[mt][nt], wqh[ks][nt], wql[ks][nt], ah[mt], al[mt]); }
        }
        // issue K weight panel (hides under Q epilogue)
        #pragma unroll
        for (int ks = 0; ks < 6; ++ks)
            #pragma unroll
            for (int nt = 0; nt < 2; ++nt) {
                const int n = (wv*2 + nt)*16 + l16;
                wkh[ks][nt] = *(const short8*)(wsp + WKH + n*KQK_ + ks*32 + quad*8);
                wkl[ks][nt] = *(const short8*)(wsp + WKL + n*KQK_ + ks*32 + quad*8);
            }
        #pragma unroll
        for (int ct = 0; ct < 2; ++ct) {
            f32x4 bq4 = *(const f32x4*)(bq + wv*32 + ct*16 + quad*4);
            #pragma unroll
            for (int mt = 0; mt < 4; ++mt) {
                f32x4 qp;
                #pragma unroll
                for (int r = 0; r < 4; ++r) {
                    float q = aq[mt][ct][r] + bq4[r];
                    qp[r] = (q > 0.f) ? q + 1.f : __expf(q);
                }
                splitfrag(qp, qfh[mt][ct], qfl[mt][ct]);
            }
        }
    }

    // ---------------- K (normal: acc = [token][channel]) + ksum ----------------
    {
        f32x4 ak[4][2];
        #pragma unroll
        for (int mt = 0; mt < 4; ++mt)
            #pragma unroll
            for (int nt = 0; nt < 2; ++nt) ak[mt][nt] = (f32x4){0.f,0.f,0.f,0.f};
        #pragma unroll
        for (int ks = 0; ks < 6; ++ks) {
            short8 ah[4], al[4];
            #pragma unroll
            for (int mt = 0; mt < 4; ++mt) {
                ah[mt] = *(const short8*)(pool + AX_H + (mt*16 + l16)*400 + ks*64 + quad*16);
                al[mt] = *(const short8*)(pool + AX_L + (mt*16 + l16)*400 + ks*64 + quad*16);
            }
            #pragma unroll
            for (int nt = 0; nt < 2; ++nt)
                #pragma unroll
                for (int mt = 0; mt < 4; ++mt) { MFMA3(ak[mt][nt], ah[mt], al[mt], wkh[ks][nt], wkl[ks][nt]); }
        }
        // issue V weight panel (hides under K epilogue)
        #pragma unroll
        for (int ks = 0; ks < 4; ++ks)
            #pragma unroll
            for (int nt = 0; nt < 2; ++nt) {
                const int n = (wv*2 + nt)*16 + l16;
                wvh[ks][nt] = *(const short8*)(wsp + WVH + n*C_ + ks*32 + quad*8);
                wvl[ks][nt] = *(const short8*)(wsp + WVL + n*C_ + ks*32 + quad*8);
            }
        float sk[2][2] = {{0.f,0.f},{0.f,0.f}};
        #pragma unroll
        for (int nt = 0; nt < 2; ++nt) {
            float bias = bk[wv*32 + nt*16 + l16];
            #pragma unroll
            for (int mt = 0; mt < 4; ++mt) {
                f32x4 kp;
                #pragma unroll
                for (int r = 0; r < 4; ++r) {
                    float k = ak[mt][nt][r] + bias;
                    float v = (k > 0.f) ? k + 1.f : __expf(k);
                    kp[r] = v;
                    sk[mt >> 1][nt] += v;
                }
                splitfrag(kp, kfh[mt][nt], kfl[mt][nt]);
            }
        }
        #pragma unroll
        for (int tau = 0; tau < 2; ++tau)
            #pragma unroll
            for (int nt = 0; nt < 2; ++nt) {
                float s = sk[tau][nt];
                s += __shfl_xor(s, 16); s += __shfl_xor(s, 32);
                if (quad == 0) ksum[tau*128 + wv*32 + nt*16 + l16] = s;
            }
    }

    // ---------------- V (normal) ----------------
    {
        f32x4 av[4][2];
        #pragma unroll
        for (int mt = 0; mt < 4; ++mt)
            #pragma unroll
            for (int nt = 0; nt < 2; ++nt) av[mt][nt] = (f32x4){0.f,0.f,0.f,0.f};
        #pragma unroll
        for (int ks = 0; ks < 4; ++ks) {
            short8 ah[4], al[4];
            #pragma unroll
            for (int mt = 0; mt < 4; ++mt) {
                ah[mt] = *(const short8*)(pool + AX_H + (mt*16 + l16)*400 + ks*64 + quad*16);
                al[mt] = *(const short8*)(pool + AX_L + (mt*16 + l16)*400 + ks*64 + quad*16);
            }
            #pragma unroll
            for (int nt = 0; nt < 2; ++nt)
                #pragma unroll
                for (int mt = 0; mt < 4; ++mt) { MFMA3(av[mt][nt], ah[mt], al[mt], wvh[ks][nt], wvl[ks][nt]); }
        }
        #pragma unroll
        for (int nt = 0; nt < 2; ++nt) {
            float bias = bv[wv*32 + nt*16 + l16];
            #pragma unroll
            for (int mt = 0; mt < 4; ++mt) {
                f32x4 vp;
                #pragma unroll
                for (int r = 0; r < 4; ++r) vp[r] = av[mt][nt][r] + bias;
                splitfrag(vp, vfh[mt][nt], vfl[mt][nt]);
            }
        }
    }

    // ---- zden (wave-local per tile) ----
    #pragma unroll
    for (int tau = 0; tau < 2; ++tau) {
        f32x4 ka0 = *(const f32x4*)(ksum + tau*128 + wv*32 + quad*4);
        f32x4 ka1 = *(const f32x4*)(ksum + tau*128 + wv*32 + 16 + quad*4);
        #pragma unroll
        for (int lt = 0; lt < 2; ++lt) {
            const int mt = tau*2 + lt;
            float p = 0.f;
            #pragma unroll
            for (int i = 0; i < 4; ++i) {
                p = fmaf(b2f((u16)(short)qfh[mt][0][i]) + b2f((u16)(short)qfl[mt][0][i]), ka0[i], p);
                p = fmaf(b2f((u16)(short)qfh[mt][1][i]) + b2f((u16)(short)qfl[mt][1][i]), ka1[i], p);
            }
            p += __shfl_xor(p, 16); p += __shfl_xor(p, 32);
            if (quad == 0) zf[tau*128 + wv*32 + lt*16 + l16] = 1.f / (p + 1e-6f);
        }
    }

    // ---- KV in registers per tile ----
    short4v kvfh[2][2][2], kvfl[2][2][2];   // [tau][dt][vt]: B-frag col=v(l16), k=d(quad*4+i)
    #pragma unroll
    for (int tau = 0; tau < 2; ++tau)
        #pragma unroll
        for (int dt = 0; dt < 2; ++dt)
            #pragma unroll
            for (int vt = 0; vt < 2; ++vt) {
                f32x4 kv = (f32x4){0.f,0.f,0.f,0.f};
                #pragma unroll
                for (int lt = 0; lt < 2; ++lt) {
                    const int mt = tau*2 + lt;
                    MFMA3_16(kv, kfh[mt][dt], kfl[mt][dt], vfh[mt][vt], vfl[mt][vt]);
                }
                splitfrag(kv, kvfh[tau][dt][vt], kvfl[tau][dt][vt]);
            }

    // ---- ln1 stats (4 threads/row, 64 rows) ----
    {
        int t = tid >> 2, jj = tid & 3;
        const char* rp = pool + AX_H + t*400 + jj*64;
        float m = 0.f, s = 0.f;
        #pragma unroll
        for (int p8 = 0; p8 < 4; ++p8) {
            short8 h = *(const short8*)(rp + p8*16);
            short8 l = *(const short8*)(rp + (AX_L - AX_H) + p8*16);
            #pragma unroll
            for (int i = 0; i < 8; ++i) {
                float v = b2f((u16)h[i]) + b2f((u16)l[i]);
                m += v; s = fmaf(v, v, s);
            }
        }
        m += __shfl_xor(m, 1); s += __shfl_xor(s, 1);
        m += __shfl_xor(m, 2); s += __shfl_xor(s, 2);
        if (jj == 0) {
            float mu = m * (1.f/C_);
            stats[t]      = mu;
            stats[64 + t] = rsqrtf(s * (1.f/C_) - mu*mu + 1e-5f);
        }
    }
    __syncthreads();

    // ---- Phase O: o = Q' x KV + zden + ln1 residual ----
    f32x4 o1v[4][2];   // [mt][vt]: row = mt*16+quad*4+r, ch = wv*32+vt*16+l16
    #pragma unroll
    for (int mt = 0; mt < 4; ++mt) {
        const int tau = mt >> 1;
        f32x4 zd4 = *(const f32x4*)(zf + tau*128 + wv*32 + (mt & 1)*16 + quad*4);
        f32x4 mu4 = *(const f32x4*)(stats + mt*16 + quad*4);
        f32x4 rs4 = *(const f32x4*)(stats + 64 + mt*16 + quad*4);
        #pragma unroll
        for (int vt = 0; vt < 2; ++vt) {
            f32x4 oa = (f32x4){0.f,0.f,0.f,0.f};
            #pragma unroll
            for (int dt = 0; dt < 2; ++dt) {
                MFMA3_16(oa, qfh[mt][dt], qfl[mt][dt], kvfh[tau][dt][vt], kvfl[tau][dt][vt]);
            }
            int ch = wv*32 + vt*16 + l16;
            float g1c = g1[ch], be1c = be1[ch];
            #pragma unroll
            for (int r = 0; r < 4; ++r) {
                int row = mt*16 + quad*4 + r;
                float xv = b2f(*(const u16*)(pool + AX_H + row*400 + ch*2))
                         + b2f(*(const u16*)(pool + AX_L + row*400 + ch*2));
                o1v[mt][vt][r] = oa[r]*zd4[r] + (xv - mu4[r])*rs4[r]*g1c + be1c;
            }
        }
    }
    // ln2 partials: per wave, 32 channels per row
    {
        #pragma unroll
        for (int mt = 0; mt < 4; ++mt)
            #pragma unroll
            for (int r = 0; r < 4; ++r) {
                float v0 = o1v[mt][0][r], v1 = o1v[mt][1][r];
                float m = v0 + v1;
                float s = v0*v0 + v1*v1;
                m += __shfl_xor(m, 1); s += __shfl_xor(s, 1);
                m += __shfl_xor(m, 2); s += __shfl_xor(s, 2);
                m += __shfl_xor(m, 4); s += __shfl_xor(s, 4);
                m += __shfl_xor(m, 8); s += __shfl_xor(s, 8);
                if (l16 == 0) {
                    int row = mt*16 + quad*4 + r;
                    ln2p[wv*64 + row]       = m;
                    ln2p[256 + wv*64 + row] = s;
                }
            }
    }
    __syncthreads();   // AX dead; LN2P visible

    // ---- X2 = raw o1 split planes; preload W1 panel for mh=0 ----
    short8 w1h[4][2], w1l[4][2], w2h[4][2], w2l[4][2];
    #pragma unroll
    for (int ks = 0; ks < 4; ++ks)
        #pragma unroll
        for (int nt = 0; nt < 2; ++nt) {
            const int gn = (wv*2 + nt)*16 + l16;
            w1h[ks][nt] = *(const short8*)(wsp + W1H + gn*C_ + ks*32 + quad*8);
            w1l[ks][nt] = *(const short8*)(wsp + W1L + gn*C_ + ks*32 + quad*8);
        }
    #pragma unroll
    for (int mt = 0; mt < 4; ++mt) {
        char* xb = pool + X2G(mt);
        #pragma unroll
        for (int vt = 0; vt < 2; ++vt) {
            int ch = wv*32 + vt*16 + l16;
            #pragma unroll
            for (int r = 0; r < 4; ++r) {
                u16 hb, lb; split2(o1v[mt][vt][r], hb, lb);
                int off = (quad*4 + r)*272 + ch*2;
                *(u16*)(xb + off)        = hb;
                *(u16*)(xb + 4352 + off) = lb;
            }
        }
    }
    if (tid < 64) {    // ln2 finalize
        int t = tid;
        float m = 0.f, s = 0.f;
        #pragma unroll
        for (int w = 0; w < 4; ++w) { m += ln2p[w*64 + t]; s += ln2p[256 + w*64 + t]; }
        float mu = m * (1.f/C_);
        float rs = rsqrtf(s * (1.f/C_) - mu*mu + 1e-5f);
        stats[128 + t] = mu * rs;
        stats[192 + t] = rs;
    }
    __syncthreads();

    // ---- Phases F/G: MLP, 4 chunks of 128, W1/W2 panels in registers ----
    f32x4 accO[4][2];   // [mt][nt]: row = mt*16+quad*4+r, out_ch = (wv*2+nt)*16+l16
    #pragma unroll
    for (int mt = 0; mt < 4; ++mt)
        #pragma unroll
        for (int nt = 0; nt < 2; ++nt) accO[mt][nt] = (f32x4){0.f,0.f,0.f,0.f};

    #pragma unroll 1
    for (int mh = 0; mh < 4; ++mh) {
        {
            f32x4 accH[4][2];
            #pragma unroll
            for (int mt = 0; mt < 4; ++mt)
                #pragma unroll
                for (int nt = 0; nt < 2; ++nt) accH[mt][nt] = (f32x4){0.f,0.f,0.f,0.f};
            #pragma unroll
            for (int ks = 0; ks < 4; ++ks) {
                short8 ah[4], al[4];
                #pragma unroll
                for (int mt = 0; mt < 4; ++mt) {
                    const char* xb = pool + X2G(mt) + l16*272 + ks*64 + quad*16;
                    ah[mt] = *(const short8*)(xb);
                    al[mt] = *(const short8*)(xb + 4352);
                }
                #pragma unroll
                for (int nt = 0; nt < 2; ++nt)
                    #pragma unroll
                    for (int mt = 0; mt < 4; ++mt) { MFMA3(accH[mt][nt], w1h[ks][nt], w1l[ks][nt], ah[mt], al[mt]); }
            }
            // issue W2 panel for this chunk (hides under F epilogue)
            #pragma unroll
            for (int ks = 0; ks < 4; ++ks)
                #pragma unroll
                for (int nt = 0; nt < 2; ++nt) {
                    const int n = (wv*2 + nt)*16 + l16;
                    w2h[ks][nt] = *(const short8*)(wsp + W2H + n*C4_ + mh*128 + ks*32 + quad*8);
                    w2l[ks][nt] = *(const short8*)(wsp + W2L + n*C4_ + mh*128 + ks*32 + quad*8);
                }
            // F epilogue: folded-ln2 + gelu -> HM
            #pragma unroll
            for (int nt = 0; nt < 2; ++nt) {
                int base = mh*128 + (wv*2 + nt)*16 + quad*4;
                f32x4 a4 = *(const f32x4*)(acf + ACF_A + base);
                f32x4 c4 = *(const f32x4*)(acf + ACF_C + base);
                int ch0 = (wv*2 + nt)*16 + quad*4;
                #pragma unroll
                for (int mt = 0; mt < 4; ++mt) {
                    int tk = mt*16 + l16;
                    float mrs = stats[128 + tk], rsv = stats[192 + tk];
                    u16 hh[4], ll[4];
                    #pragma unroll
                    for (int r = 0; r < 4; ++r) {
                        float v = accH[mt][nt][r]*rsv - mrs*a4[r] + c4[r];
                        float ge = 0.5f * v * (1.f + erff(v * 0.70710678118654752f));
                        split2(ge, hh[r], ll[r]);
                    }
                    char* hb = pool + HM_H + tk*272 + ch0*2;
                    *(u16x4*)(hb)                    = (u16x4){hh[0],hh[1],hh[2],hh[3]};
                    *(u16x4*)(hb + (HM_L - HM_H))    = (u16x4){ll[0],ll[1],ll[2],ll[3]};
                }
            }
        }
        __syncthreads();
        {
            #pragma unroll
            for (int ks = 0; ks < 4; ++ks) {
                short8 ah[4], al[4];
                #pragma unroll
                for (int mt = 0; mt < 4; ++mt) {
                    const char* hb = pool + HM_H + (mt*16 + l16)*272 + ks*64 + quad*16;
                    ah[mt] = *(const short8*)(hb);
                    al[mt] = *(const short8*)(hb + (HM_L - HM_H));
                }
                #pragma unroll
                for (int nt = 0; nt < 2; ++nt)
                    #pragma unroll
                    for (int mt = 0; mt < 4; ++mt) { MFMA3(accO[mt][nt], ah[mt], al[mt], w2h[ks][nt], w2l[ks][nt]); }
            }
            // issue W1 panel for next chunk (hides under G + barrier)
            if (mh < 3) {
                #pragma unroll
                for (int ks = 0; ks < 4; ++ks)
                    #pragma unroll
                    for (int nt = 0; nt < 2; ++nt) {
                        const int gn = (mh+1)*128 + (wv*2 + nt)*16 + l16;
                        w1h[ks][nt] = *(const short8*)(wsp + W1H + gn*C_ + ks*32 + quad*8);
                        w1l[ks][nt] = *(const short8*)(wsp + W1L + gn*C_ + ks*32 + quad*8);
                    }
            }
        }
        if (mh < 3) __syncthreads();
    }

    // ---- Epilogue: y = o1v + mlp + b2, strided store (two tiles) ----
    {
        float* obase = out + (size_t)b * (T_*C_*HW_) + hw0;
        #pragma unroll
        for (int mt = 0; mt < 4; ++mt) {
            const int tau = mt >> 1;
            float* ob = obase + tau;
            #pragma unroll
            for (int nt = 0; nt < 2; ++nt) {
                int ch = wv*32 + nt*16 + l16;
                float b2c = b2[ch];
                #pragma unroll
                for (int r = 0; r < 4; ++r) {
                    int t = (mt & 1)*16 + quad*4 + r;
                    float y = o1v[mt][nt][r] + accO[mt][nt][r] + b2c;
                    ob[(size_t)(t*C_ + ch) * HW_] = y;
                }
            }
        }
    }
}

extern "C" void kernel_launch(void* const* d_in, const int* in_sizes, int n_in,
                              void* d_out, int out_size, void* d_ws, size_t ws_size,
                              hipStream_t stream)
{
    const float* x   = (const float*)d_in[0];
    const float* gui = (const float*)d_in[1];
    const float* Wq  = (const float*)d_in[2];
    const float* bq  = (const float*)d_in[3];
    const float* Wk  = (const float*)d_in[4];
    const float* bk  = (const float*)d_in[5];
    const float* Wv  = (const float*)d_in[6];
    const float* bv  = (const float*)d_in[7];
    const float* g1  = (const float*)d_in[8];
    const float* be1 = (const float*)d_in[9];
    const float* g2  = (const float*)d_in[10];
    const float* be2 = (const float*)d_in[11];
    const float* W1  = (const float*)d_in[12];
    const float* b1  = (const float*)d_in[13];
    const float* W2  = (const float*)d_in[14];
    const float* b2  = (const float*)d_in[15];
    u16* wsp = (u16*)d_ws;

    int use_xt = (ws_size >= WS_NEED_BYTES) ? 1 : 0;

    prep_weights<<<dim3(802), dim3(256), 0, stream>>>(Wq, Wk, Wv, W1, W2, gui, g2, be2, b1, wsp);
    if (use_xt)
        transpose_x<<<dim3(8192), dim3(256), 0, stream>>>(x, wsp);

    (void)hipFuncSetAttribute((const void*)fused_linattn_mfma,
                              hipFuncAttributeMaxDynamicSharedMemorySize,
                              POOLB);
    fused_linattn_mfma<<<dim3(2048), dim3(256), POOLB, stream>>>(
        x, bq, bk, bv, g1, be1, b2, wsp, use_xt, (float*)d_out);
}

// Round 9
// 428.949 us; speedup vs baseline: 1.8088x; 1.1320x over previous
//
#include <hip/hip_runtime.h>
#include <hip/hip_bf16.h>
#include <math.h>

#define T_   32
#define C_   128
#define GD_  64
#define KQK_ 192
#define NH_  4
#define HD_  32
#define C4_  512
#define HW_  1024

typedef unsigned short u16;
typedef __attribute__((ext_vector_type(8))) short short8;
typedef __attribute__((ext_vector_type(4))) short short4v;
typedef __attribute__((ext_vector_type(4))) float f32x4;
typedef __attribute__((ext_vector_type(4))) unsigned short u16x4;

// ---- ws layout ----
#define ACF_A 0
#define ACF_C 512
#define WQH 2048
#define WQL 26624
#define WKH 51200
#define WKL 75776
#define WVH 100352
#define WVL 116736
#define W1H 133120
#define W1L 198656
#define W2H 264192
#define W2L 329728
#define GSH 395264
#define GSL 403456
#define XT  411648           // per-n interleaved: [n][hi 4096 u16 | lo 4096 u16]
#define WS_NEED_BYTES (823296ull + 4096ull*8192ull*2ull)   // 67,932,160

// ---- LDS pool byte offsets (M=64: two sequences per block) ----
#define AX_H  0        // [64][200] u16 (x|g hi), stride 400 B; rows 0-31 tile0, 32-63 tile1
#define AX_L  25600    // lo plane, ends 51200
// X2: 4 groups of 16 rows, overlaying AX after it dies. group g at g*8704:
//   h [16][136] stride 272 at +0, l at +4352. Ends 34816.
#define X2G(g) ((g)*8704)
#define HM_H  34816    // [64][136] u16 stride 272 (h), 17408 B
#define HM_L  52224    // lo plane, ends 69632
#define KSUM  69632    // 256 f32: [tile][128]
#define ZDEN  70656    // 256 f32: [tile][head*32+token]
#define STATS 71680    // 256 f32: mu1[64] rs1[64] mu2*rs2[64] rs2[64]
#define LN2P  72704    // 512 f32: m[4 waves][64 rows], s[4][64]
#define POOLB 74752    // 2 blocks/CU (163840/2 = 81920)

__device__ __forceinline__ float b2f(u16 u) {
    unsigned int x = ((unsigned int)u) << 16;
    float f; __builtin_memcpy(&f, &x, 4); return f;
}
__device__ __forceinline__ u16 f2b(float f) {
    __hip_bfloat16 h = __float2bfloat16(f);
    u16 u; __builtin_memcpy(&u, &h, 2); return u;
}
__device__ __forceinline__ void split2(float v, u16& h, u16& l) {
    h = f2b(v); l = f2b(v - b2f(h));
}
__device__ __forceinline__ void splitfrag(const f32x4 v, short4v& h, short4v& l) {
    u16 hh[4], ll[4];
    #pragma unroll
    for (int r = 0; r < 4; ++r) { hh[r] = f2b(v[r]); ll[r] = f2b(v[r] - b2f(hh[r])); }
    h = (short4v){(short)hh[0],(short)hh[1],(short)hh[2],(short)hh[3]};
    l = (short4v){(short)ll[0],(short)ll[1],(short)ll[2],(short)ll[3]};
}

// Branch-free gelu via Abramowitz-Stegun 7.1.26 erf approx (max err 1.5e-7).
// gelu(v) = 0.5 v (1 + erf(v/sqrt2)); for u>=0: erf(u)=1-P(u), so ge = v - 0.5v*P;
// for u<0: ge = 0.5v*P(|u|).
__device__ __forceinline__ float gelu_fast(float v) {
    float a  = fabsf(v) * 0.70710678118654752f;
    float t  = __builtin_amdgcn_rcpf(fmaf(a, 0.3275911f, 1.f));
    float p  = t*(0.254829592f + t*(-0.284496736f + t*(1.421413741f
             + t*(-1.453152027f + t*1.061405429f))));
    float P  = p * __expf(-a*a);
    float hv = 0.5f * v;
    return (v > 0.f) ? v - hv*P : hv*P;
}

__device__ __forceinline__ f32x4 mfma16(short4v a, short4v b, f32x4 c) {
#if __has_builtin(__builtin_amdgcn_mfma_f32_16x16x16bf16_1k)
    return __builtin_amdgcn_mfma_f32_16x16x16bf16_1k(a, b, c, 0, 0, 0);
#else
    asm("v_mfma_f32_16x16x16_bf16 %0, %1, %2, %0" : "+v"(c) : "v"(a), "v"(b));
    return c;
#endif
}

#define MFMA3(acc, ah, al, bh, bl)                                          \
    acc = __builtin_amdgcn_mfma_f32_16x16x32_bf16(ah, bh, acc, 0, 0, 0);    \
    acc = __builtin_amdgcn_mfma_f32_16x16x32_bf16(ah, bl, acc, 0, 0, 0);    \
    acc = __builtin_amdgcn_mfma_f32_16x16x32_bf16(al, bh, acc, 0, 0, 0);

#define MFMA3_16(acc, ah, al, bh, bl)                                       \
    acc = mfma16(ah, bh, acc);                                              \
    acc = mfma16(ah, bl, acc);                                              \
    acc = mfma16(al, bh, acc);

// ---- prep: split weights + guidance + a/cpl (unchanged) ----
__global__ void prep_weights(const float* __restrict__ Wq, const float* __restrict__ Wk,
                             const float* __restrict__ Wv, const float* __restrict__ W1,
                             const float* __restrict__ W2, const float* __restrict__ gui,
                             const float* __restrict__ g2, const float* __restrict__ be2,
                             const float* __restrict__ b1,
                             u16* __restrict__ wsp)
{
    int e = blockIdx.x * 256 + threadIdx.x;
    if (e >= 204800) {
        int n = e - 204800;
        if (n >= 512) return;
        float a = 0.f, c = 0.f;
        for (int k = 0; k < 128; ++k) {
            float w = W1[k*512 + n];
            a = fmaf(w, g2[k], a);
            c = fmaf(w, be2[k], c);
        }
        float* acf = (float*)wsp;
        acf[ACF_A + n] = a;
        acf[ACF_C + n] = c + b1[n];
        return;
    }
    if (e >= 196608) {
        int idx = e - 196608;
        float v = gui[idx];
        u16 hb = f2b(v);
        wsp[GSH + idx] = hb;
        wsp[GSL + idx] = f2b(v - b2f(hb));
        return;
    }
    const float* src; int e2, k, n, K; int oh, ol; int isW1 = 0;
    if (e < 24576)       { src = Wq; e2 = e;          k = e2 >> 7; n = e2 & 127; K = KQK_; oh = WQH; ol = WQL; }
    else if (e < 49152)  { src = Wk; e2 = e - 24576;  k = e2 >> 7; n = e2 & 127; K = KQK_; oh = WKH; ol = WKL; }
    else if (e < 65536)  { src = Wv; e2 = e - 49152;  k = e2 >> 7; n = e2 & 127; K = C_;   oh = WVH; ol = WVL; }
    else if (e < 131072) { src = W1; e2 = e - 65536;  k = e2 >> 9; n = e2 & 511; K = C_;   oh = W1H; ol = W1L; isW1 = 1; }
    else                 { src = W2; e2 = e - 131072; k = e2 >> 7; n = e2 & 127; K = C4_;  oh = W2H; ol = W2L; }
    float w = src[e2];
    if (isW1) w *= g2[k];
    u16 hb = f2b(w);
    wsp[oh + n * K + k] = hb;
    wsp[ol + n * K + k] = f2b(w - b2f(hb));
}

// ---- transpose x (unchanged) ----
__global__ __launch_bounds__(256) void transpose_x(const float* __restrict__ x, u16* __restrict__ wsp)
{
    __shared__ float tile[32][65];
    int bid = blockIdx.x;
    int hq = bid & 15, cq = (bid >> 4) & 3, t = (bid >> 6) & 31, b = bid >> 11;
    int c0 = cq * 32, hw0 = hq * 64;
    int tid = threadIdx.x;
    {
        int i = tid >> 3, j8 = (tid & 7) * 8;
        const float* src = x + ((size_t)((b*32 + t)*128 + c0 + i))*1024 + hw0 + j8;
        float4 v0 = *reinterpret_cast<const float4*>(src);
        float4 v1 = *reinterpret_cast<const float4*>(src + 4);
        tile[i][j8+0]=v0.x; tile[i][j8+1]=v0.y; tile[i][j8+2]=v0.z; tile[i][j8+3]=v0.w;
        tile[i][j8+4]=v1.x; tile[i][j8+5]=v1.y; tile[i][j8+6]=v1.z; tile[i][j8+7]=v1.w;
    }
    __syncthreads();
    {
        int jj = tid >> 2, c8 = (tid & 3) * 8;
        int n = b*1024 + hw0 + jj;
        u16 hh[8], ll[8];
        #pragma unroll
        for (int ii = 0; ii < 8; ++ii) {
            float v = tile[c8 + ii][jj];
            u16 hb = f2b(v);
            hh[ii] = hb; ll[ii] = f2b(v - b2f(hb));
        }
        u16* dh = wsp + XT + (size_t)n*8192 + t*128 + c0 + c8;
        u16* dl = dh + 4096;
        *reinterpret_cast<ushort4*>(dh)     = make_ushort4(hh[0],hh[1],hh[2],hh[3]);
        *reinterpret_cast<ushort4*>(dh + 4) = make_ushort4(hh[4],hh[5],hh[6],hh[7]);
        *reinterpret_cast<ushort4*>(dl)     = make_ushort4(ll[0],ll[1],ll[2],ll[3]);
        *reinterpret_cast<ushort4*>(dl + 4) = make_ushort4(ll[4],ll[5],ll[6],ll[7]);
    }
}

__global__ __launch_bounds__(256, 2) void fused_linattn_mfma(
    const float* __restrict__ x,
    const float* __restrict__ bq, const float* __restrict__ bk, const float* __restrict__ bv,
    const float* __restrict__ g1, const float* __restrict__ be1,
    const float* __restrict__ b2,
    const u16* __restrict__ wsp, int use_xt,
    float* __restrict__ out)
{
    extern __shared__ __align__(16) char pool[];
    float* ksum  = (float*)(pool + KSUM);
    float* zf    = (float*)(pool + ZDEN);
    float* stats = (float*)(pool + STATS);
    float* ln2p  = (float*)(pool + LN2P);
    const float* acf = (const float*)wsp;

    const int bi  = blockIdx.x;                    // 0..2047
    const int j_  = ((bi & 7) << 8) | (bi >> 3);   // XCD-chunked
    const int n0  = j_ * 2;                        // tiles n0, n0+1 (same b)
    const int b   = n0 >> 10;
    const int hw0 = n0 & 1023;
    const int tid = threadIdx.x;
    const int lane = tid & 63, wv = tid >> 6;
    const int l16  = lane & 15, quad = lane >> 4;

    // ---- Preload Q weight panel (hidden under phase A) ----
    short8 wqh[6][2], wql[6][2];
    #pragma unroll
    for (int ks = 0; ks < 6; ++ks)
        #pragma unroll
        for (int nt = 0; nt < 2; ++nt) {
            const int n = (wv*2 + nt)*16 + l16;
            wqh[ks][nt] = *(const short8*)(wsp + WQH + n*KQK_ + ks*32 + quad*8);
            wql[ks][nt] = *(const short8*)(wsp + WQL + n*KQK_ + ks*32 + quad*8);
        }

    // ---- Phase A: stage both tiles into AX ----
    if (use_xt) {
        #pragma unroll
        for (int tau = 0; tau < 2; ++tau) {
            const u16* xtb = wsp + XT + (size_t)(n0 + tau) * 8192;
            #pragma unroll
            for (int i = 0; i < 2; ++i) {
                int off = (tid + i*256) * 8;
                int t = off >> 7, c = off & 127;
                short8 vh = *reinterpret_cast<const short8*>(xtb + off);
                short8 vl = *reinterpret_cast<const short8*>(xtb + 4096 + off);
                *reinterpret_cast<short8*>(pool + AX_H + (tau*32 + t)*400 + c*2) = vh;
                *reinterpret_cast<short8*>(pool + AX_L + (tau*32 + t)*400 + c*2) = vl;
            }
        }
    } else {
        #pragma unroll
        for (int tau = 0; tau < 2; ++tau) {
            const float* xb = x + (size_t)b * (T_*C_*HW_) + hw0 + tau;
            #pragma unroll
            for (int i = 0; i < 16; ++i) {
                int idx = tid + i*256;
                float v = xb[(size_t)idx * HW_];
                int t = idx >> 7, c = idx & 127;
                u16 hb = f2b(v);
                *(u16*)(pool + AX_H + (tau*32 + t)*400 + c*2) = hb;
                *(u16*)(pool + AX_L + (tau*32 + t)*400 + c*2) = f2b(v - b2f(hb));
            }
        }
    }
    {   // guidance: same b for both tiles -> write rows t and t+32
        const u16* gh = wsp + GSH + b*2048 + tid*8;
        const u16* gl = wsp + GSL + b*2048 + tid*8;
        int off = tid * 8;
        int t = off >> 6, jg = off & 63;
        short8 vh = *reinterpret_cast<const short8*>(gh);
        short8 vl = *reinterpret_cast<const short8*>(gl);
        *reinterpret_cast<short8*>(pool + AX_H + t*400 + 256 + jg*2) = vh;
        *reinterpret_cast<short8*>(pool + AX_L + t*400 + 256 + jg*2) = vl;
        *reinterpret_cast<short8*>(pool + AX_H + (32 + t)*400 + 256 + jg*2) = vh;
        *reinterpret_cast<short8*>(pool + AX_L + (32 + t)*400 + 256 + jg*2) = vl;
    }
    __syncthreads();

    // ---- Phase B: Q, K, V GEMMs over M=64 ----
    short4v qfh[4][2], qfl[4][2];   // [mt][dt]: Q' A-frag: row=token(l16), k=d(quad*4+i)
    short4v kfh[4][2], kfl[4][2];   // [mt][dt]: K' A-frag: row=d(l16), k=token(quad*4+i)
    short4v vfh[4][2], vfl[4][2];   // [mt][vt]: V  B-frag: col=v(l16), k=token(quad*4+i)

    // ---------------- Q (swapped: acc = [channel][token]) ----------------
    {
        f32x4 aq[4][2];
        #pragma unroll
        for (int mt = 0; mt < 4; ++mt)
            #pragma unroll
            for (int nt = 0; nt < 2; ++nt) aq[mt][nt] = (f32x4){0.f,0.f,0.f,0.f};
        #pragma unroll
        for (int ks = 0; ks < 6; ++ks) {
            short8 ah[4], al[4];
            #pragma unroll
            for (int mt = 0; mt < 4; ++mt) {
                ah[mt] = *(const short8*)(pool + AX_H + (mt*16 + l16)*400 + ks*64 + quad*16);
                al[mt] = *(const short8*)(pool + AX_L + (mt*16 + l16)*400 + ks*64 + quad*16);
            }
            #pragma unroll
            for (int nt = 0; nt < 2; ++nt)
                #pragma unroll
                for (int mt = 0; mt < 4; ++mt) { MFMA3(aq[mt][nt], wqh[ks][nt], wql[ks][nt], ah[mt], al[mt]); }
        }
        #pragma unroll
        for (int ct = 0; ct < 2; ++ct) {
            f32x4 bq4 = *(const f32x4*)(bq + wv*32 + ct*16 + quad*4);
            #pragma unroll
            for (int mt = 0; mt < 4; ++mt) {
                f32x4 qp;
                #pragma unroll
                for (int r = 0; r < 4; ++r) {
                    float q = aq[mt][ct][r] + bq4[r];
                    qp[r] = (q > 0.f) ? q + 1.f : __expf(q);
                }
                splitfrag(qp, qfh[mt][ct], qfl[mt][ct]);
            }
        }
    }

    // ---------------- K (normal: acc = [token][channel]) + ksum ----------------
    {
        f32x4 ak[4][2];
        #pragma unroll
        for (int mt = 0; mt < 4; ++mt)
            #pragma unroll
            for (int nt = 0; nt < 2; ++nt) ak[mt][nt] = (f32x4){0.f,0.f,0.f,0.f};
        #pragma unroll
        for (int ks = 0; ks < 6; ++ks) {
            short8 ah[4], al[4];
            #pragma unroll
            for (int mt = 0; mt < 4; ++mt) {
                ah[mt] = *(const short8*)(pool + AX_H + (mt*16 + l16)*400 + ks*64 + quad*16);
                al[mt] = *(const short8*)(pool + AX_L + (mt*16 + l16)*400 + ks*64 + quad*16);
            }
            #pragma unroll
            for (int nt = 0; nt < 2; ++nt) {
                const int n = (wv*2 + nt)*16 + l16;
                short8 bh = *(const short8*)(wsp + WKH + n*KQK_ + ks*32 + quad*8);
                short8 bl = *(const short8*)(wsp + WKL + n*KQK_ + ks*32 + quad*8);
                #pragma unroll
                for (int mt = 0; mt < 4; ++mt) { MFMA3(ak[mt][nt], ah[mt], al[mt], bh, bl); }
            }
        }
        float sk[2][2] = {{0.f,0.f},{0.f,0.f}};
        #pragma unroll
        for (int nt = 0; nt < 2; ++nt) {
            float bias = bk[wv*32 + nt*16 + l16];
            #pragma unroll
            for (int mt = 0; mt < 4; ++mt) {
                f32x4 kp;
                #pragma unroll
                for (int r = 0; r < 4; ++r) {
                    float k = ak[mt][nt][r] + bias;
                    float v = (k > 0.f) ? k + 1.f : __expf(k);
                    kp[r] = v;
                    sk[mt >> 1][nt] += v;
                }
                splitfrag(kp, kfh[mt][nt], kfl[mt][nt]);
            }
        }
        #pragma unroll
        for (int tau = 0; tau < 2; ++tau)
            #pragma unroll
            for (int nt = 0; nt < 2; ++nt) {
                float s = sk[tau][nt];
                s += __shfl_xor(s, 16); s += __shfl_xor(s, 32);
                if (quad == 0) ksum[tau*128 + wv*32 + nt*16 + l16] = s;
            }
    }

    // ---------------- V (normal) ----------------
    {
        f32x4 av[4][2];
        #pragma unroll
        for (int mt = 0; mt < 4; ++mt)
            #pragma unroll
            for (int nt = 0; nt < 2; ++nt) av[mt][nt] = (f32x4){0.f,0.f,0.f,0.f};
        #pragma unroll
        for (int ks = 0; ks < 4; ++ks) {
            short8 ah[4], al[4];
            #pragma unroll
            for (int mt = 0; mt < 4; ++mt) {
                ah[mt] = *(const short8*)(pool + AX_H + (mt*16 + l16)*400 + ks*64 + quad*16);
                al[mt] = *(const short8*)(pool + AX_L + (mt*16 + l16)*400 + ks*64 + quad*16);
            }
            #pragma unroll
            for (int nt = 0; nt < 2; ++nt) {
                const int n = (wv*2 + nt)*16 + l16;
                short8 bh = *(const short8*)(wsp + WVH + n*C_ + ks*32 + quad*8);
                short8 bl = *(const short8*)(wsp + WVL + n*C_ + ks*32 + quad*8);
                #pragma unroll
                for (int mt = 0; mt < 4; ++mt) { MFMA3(av[mt][nt], ah[mt], al[mt], bh, bl); }
            }
        }
        #pragma unroll
        for (int nt = 0; nt < 2; ++nt) {
            float bias = bv[wv*32 + nt*16 + l16];
            #pragma unroll
            for (int mt = 0; mt < 4; ++mt) {
                f32x4 vp;
                #pragma unroll
                for (int r = 0; r < 4; ++r) vp[r] = av[mt][nt][r] + bias;
                splitfrag(vp, vfh[mt][nt], vfl[mt][nt]);
            }
        }
    }

    // ---- zden (wave-local per tile) ----
    #pragma unroll
    for (int tau = 0; tau < 2; ++tau) {
        f32x4 ka0 = *(const f32x4*)(ksum + tau*128 + wv*32 + quad*4);
        f32x4 ka1 = *(const f32x4*)(ksum + tau*128 + wv*32 + 16 + quad*4);
        #pragma unroll
        for (int lt = 0; lt < 2; ++lt) {
            const int mt = tau*2 + lt;
            float p = 0.f;
            #pragma unroll
            for (int i = 0; i < 4; ++i) {
                p = fmaf(b2f((u16)(short)qfh[mt][0][i]) + b2f((u16)(short)qfl[mt][0][i]), ka0[i], p);
                p = fmaf(b2f((u16)(short)qfh[mt][1][i]) + b2f((u16)(short)qfl[mt][1][i]), ka1[i], p);
            }
            p += __shfl_xor(p, 16); p += __shfl_xor(p, 32);
            if (quad == 0) zf[tau*128 + wv*32 + lt*16 + l16] = 1.f / (p + 1e-6f);
        }
    }

    // ---- KV in registers per tile ----
    short4v kvfh[2][2][2], kvfl[2][2][2];   // [tau][dt][vt]: B-frag col=v(l16), k=d(quad*4+i)
    #pragma unroll
    for (int tau = 0; tau < 2; ++tau)
        #pragma unroll
        for (int dt = 0; dt < 2; ++dt)
            #pragma unroll
            for (int vt = 0; vt < 2; ++vt) {
                f32x4 kv = (f32x4){0.f,0.f,0.f,0.f};
                #pragma unroll
                for (int lt = 0; lt < 2; ++lt) {
                    const int mt = tau*2 + lt;
                    MFMA3_16(kv, kfh[mt][dt], kfl[mt][dt], vfh[mt][vt], vfl[mt][vt]);
                }
                splitfrag(kv, kvfh[tau][dt][vt], kvfl[tau][dt][vt]);
            }

    // ---- ln1 stats (4 threads/row, 64 rows) ----
    {
        int t = tid >> 2, jj = tid & 3;
        const char* rp = pool + AX_H + t*400 + jj*64;
        float m = 0.f, s = 0.f;
        #pragma unroll
        for (int p8 = 0; p8 < 4; ++p8) {
            short8 h = *(const short8*)(rp + p8*16);
            short8 l = *(const short8*)(rp + (AX_L - AX_H) + p8*16);
            #pragma unroll
            for (int i = 0; i < 8; ++i) {
                float v = b2f((u16)h[i]) + b2f((u16)l[i]);
                m += v; s = fmaf(v, v, s);
            }
        }
        m += __shfl_xor(m, 1); s += __shfl_xor(s, 1);
        m += __shfl_xor(m, 2); s += __shfl_xor(s, 2);
        if (jj == 0) {
            float mu = m * (1.f/C_);
            stats[t]      = mu;
            stats[64 + t] = rsqrtf(s * (1.f/C_) - mu*mu + 1e-5f);
        }
    }
    __syncthreads();

    // ---- Phase O: o = Q' x KV + zden + ln1 residual ----
    f32x4 o1v[4][2];   // [mt][vt]: row = mt*16+quad*4+r, ch = wv*32+vt*16+l16
    #pragma unroll
    for (int mt = 0; mt < 4; ++mt) {
        const int tau = mt >> 1;
        f32x4 zd4 = *(const f32x4*)(zf + tau*128 + wv*32 + (mt & 1)*16 + quad*4);
        f32x4 mu4 = *(const f32x4*)(stats + mt*16 + quad*4);
        f32x4 rs4 = *(const f32x4*)(stats + 64 + mt*16 + quad*4);
        #pragma unroll
        for (int vt = 0; vt < 2; ++vt) {
            f32x4 oa = (f32x4){0.f,0.f,0.f,0.f};
            #pragma unroll
            for (int dt = 0; dt < 2; ++dt) {
                MFMA3_16(oa, qfh[mt][dt], qfl[mt][dt], kvfh[tau][dt][vt], kvfl[tau][dt][vt]);
            }
            int ch = wv*32 + vt*16 + l16;
            float g1c = g1[ch], be1c = be1[ch];
            #pragma unroll
            for (int r = 0; r < 4; ++r) {
                int row = mt*16 + quad*4 + r;
                float xv = b2f(*(const u16*)(pool + AX_H + row*400 + ch*2))
                         + b2f(*(const u16*)(pool + AX_L + row*400 + ch*2));
                o1v[mt][vt][r] = oa[r]*zd4[r] + (xv - mu4[r])*rs4[r]*g1c + be1c;
            }
        }
    }
    // ln2 partials: per wave, 32 channels per row
    {
        #pragma unroll
        for (int mt = 0; mt < 4; ++mt)
            #pragma unroll
            for (int r = 0; r < 4; ++r) {
                float v0 = o1v[mt][0][r], v1 = o1v[mt][1][r];
                float m = v0 + v1;
                float s = v0*v0 + v1*v1;
                m += __shfl_xor(m, 1); s += __shfl_xor(s, 1);
                m += __shfl_xor(m, 2); s += __shfl_xor(s, 2);
                m += __shfl_xor(m, 4); s += __shfl_xor(s, 4);
                m += __shfl_xor(m, 8); s += __shfl_xor(s, 8);
                if (l16 == 0) {
                    int row = mt*16 + quad*4 + r;
                    ln2p[wv*64 + row]       = m;
                    ln2p[256 + wv*64 + row] = s;
                }
            }
    }
    __syncthreads();   // AX dead; LN2P visible

    // ---- X2 = raw o1 split planes (4 groups of 16 rows) ----
    #pragma unroll
    for (int mt = 0; mt < 4; ++mt) {
        char* xb = pool + X2G(mt);
        #pragma unroll
        for (int vt = 0; vt < 2; ++vt) {
            int ch = wv*32 + vt*16 + l16;
            #pragma unroll
            for (int r = 0; r < 4; ++r) {
                u16 hb, lb; split2(o1v[mt][vt][r], hb, lb);
                int off = (quad*4 + r)*272 + ch*2;
                *(u16*)(xb + off)        = hb;
                *(u16*)(xb + 4352 + off) = lb;
            }
        }
    }
    if (tid < 64) {    // ln2 finalize
        int t = tid;
        float m = 0.f, s = 0.f;
        #pragma unroll
        for (int w = 0; w < 4; ++w) { m += ln2p[w*64 + t]; s += ln2p[256 + w*64 + t]; }
        float mu = m * (1.f/C_);
        float rs = rsqrtf(s * (1.f/C_) - mu*mu + 1e-5f);
        stats[128 + t] = mu * rs;
        stats[192 + t] = rs;
    }
    __syncthreads();

    // ---- Phases F/G: MLP, 4 chunks of 128 ----
    f32x4 accO[4][2];   // [mt][nt]: row = mt*16+quad*4+r, out_ch = (wv*2+nt)*16+l16
    #pragma unroll
    for (int mt = 0; mt < 4; ++mt)
        #pragma unroll
        for (int nt = 0; nt < 2; ++nt) accO[mt][nt] = (f32x4){0.f,0.f,0.f,0.f};

    #pragma unroll 1
    for (int mh = 0; mh < 4; ++mh) {
        {
            f32x4 accH[4][2];
            #pragma unroll
            for (int mt = 0; mt < 4; ++mt)
                #pragma unroll
                for (int nt = 0; nt < 2; ++nt) accH[mt][nt] = (f32x4){0.f,0.f,0.f,0.f};
            #pragma unroll
            for (int ks = 0; ks < 4; ++ks) {
                short8 ah[4], al[4];
                #pragma unroll
                for (int mt = 0; mt < 4; ++mt) {
                    const char* xb = pool + X2G(mt) + l16*272 + ks*64 + quad*16;
                    ah[mt] = *(const short8*)(xb);
                    al[mt] = *(const short8*)(xb + 4352);
                }
                #pragma unroll
                for (int nt = 0; nt < 2; ++nt) {
                    const int gn = mh*128 + (wv*2 + nt)*16 + l16;
                    short8 bh = *(const short8*)(wsp + W1H + gn*C_ + ks*32 + quad*8);
                    short8 bl = *(const short8*)(wsp + W1L + gn*C_ + ks*32 + quad*8);
                    #pragma unroll
                    for (int mt = 0; mt < 4; ++mt) { MFMA3(accH[mt][nt], bh, bl, ah[mt], al[mt]); }
                }
            }
            // F epilogue: folded-ln2 + fast gelu -> HM
            #pragma unroll
            for (int nt = 0; nt < 2; ++nt) {
                int base = mh*128 + (wv*2 + nt)*16 + quad*4;
                f32x4 a4 = *(const f32x4*)(acf + ACF_A + base);
                f32x4 c4 = *(const f32x4*)(acf + ACF_C + base);
                int ch0 = (wv*2 + nt)*16 + quad*4;
                #pragma unroll
                for (int mt = 0; mt < 4; ++mt) {
                    int tk = mt*16 + l16;
                    float mrs = stats[128 + tk], rsv = stats[192 + tk];
                    u16 hh[4], ll[4];
                    #pragma unroll
                    for (int r = 0; r < 4; ++r) {
                        float v = accH[mt][nt][r]*rsv - mrs*a4[r] + c4[r];
                        float ge = gelu_fast(v);
                        split2(ge, hh[r], ll[r]);
                    }
                    char* hb = pool + HM_H + tk*272 + ch0*2;
                    *(u16x4*)(hb)                    = (u16x4){hh[0],hh[1],hh[2],hh[3]};
                    *(u16x4*)(hb + (HM_L - HM_H))    = (u16x4){ll[0],ll[1],ll[2],ll[3]};
                }
            }
        }
        __syncthreads();
        {
            #pragma unroll
            for (int ks = 0; ks < 4; ++ks) {
                short8 ah[4], al[4];
                #pragma unroll
                for (int mt = 0; mt < 4; ++mt) {
                    const char* hb = pool + HM_H + (mt*16 + l16)*272 + ks*64 + quad*16;
                    ah[mt] = *(const short8*)(hb);
                    al[mt] = *(const short8*)(hb + (HM_L - HM_H));
                }
                #pragma unroll
                for (int nt = 0; nt < 2; ++nt) {
                    const int n = (wv*2 + nt)*16 + l16;
                    short8 bh = *(const short8*)(wsp + W2H + n*C4_ + mh*128 + ks*32 + quad*8);
                    short8 bl = *(const short8*)(wsp + W2L + n*C4_ + mh*128 + ks*32 + quad*8);
                    #pragma unroll
                    for (int mt = 0; mt < 4; ++mt) { MFMA3(accO[mt][nt], ah[mt], al[mt], bh, bl); }
                }
            }
        }
        if (mh < 3) __syncthreads();
    }

    // ---- Epilogue: y = o1v + mlp + b2, strided store (two tiles) ----
    {
        float* obase = out + (size_t)b * (T_*C_*HW_) + hw0;
        #pragma unroll
        for (int mt = 0; mt < 4; ++mt) {
            const int tau = mt >> 1;
            float* ob = obase + tau;
            #pragma unroll
            for (int nt = 0; nt < 2; ++nt) {
                int ch = wv*32 + nt*16 + l16;
                float b2c = b2[ch];
                #pragma unroll
                for (int r = 0; r < 4; ++r) {
                    int t = (mt & 1)*16 + quad*4 + r;
                    float y = o1v[mt][nt][r] + accO[mt][nt][r] + b2c;
                    ob[(size_t)(t*C_ + ch) * HW_] = y;
                }
            }
        }
    }
}

extern "C" void kernel_launch(void* const* d_in, const int* in_sizes, int n_in,
                              void* d_out, int out_size, void* d_ws, size_t ws_size,
                              hipStream_t stream)
{
    const float* x   = (const float*)d_in[0];
    const float* gui = (const float*)d_in[1];
    const float* Wq  = (const float*)d_in[2];
    const float* bq  = (const float*)d_in[3];
    const float* Wk  = (const float*)d_in[4];
    const float* bk  = (const float*)d_in[5];
    const float* Wv  = (const float*)d_in[6];
    const float* bv  = (const float*)d_in[7];
    const float* g1  = (const float*)d_in[8];
    const float* be1 = (const float*)d_in[9];
    const float* g2  = (const float*)d_in[10];
    const float* be2 = (const float*)d_in[11];
    const float* W1  = (const float*)d_in[12];
    const float* b1  = (const float*)d_in[13];
    const float* W2  = (const float*)d_in[14];
    const float* b2  = (const float*)d_in[15];
    u16* wsp = (u16*)d_ws;

    int use_xt = (ws_size >= WS_NEED_BYTES) ? 1 : 0;

    prep_weights<<<dim3(802), dim3(256), 0, stream>>>(Wq, Wk, Wv, W1, W2, gui, g2, be2, b1, wsp);
    if (use_xt)
        transpose_x<<<dim3(8192), dim3(256), 0, stream>>>(x, wsp);

    (void)hipFuncSetAttribute((const void*)fused_linattn_mfma,
                              hipFuncAttributeMaxDynamicSharedMemorySize,
                              POOLB);
    fused_linattn_mfma<<<dim3(2048), dim3(256), POOLB, stream>>>(
        x, bq, bk, bv, g1, be1, b2, wsp, use_xt, (float*)d_out);
}